// Round 1
// baseline (523.296 us; speedup 1.0000x reference)
//
#include <hip/hip_runtime.h>

#define D 96

static inline size_t alignup(size_t x) { return (x + 255) & ~size_t(255); }

__global__ void count_deg_kernel(const int* __restrict__ dst, int E, int* __restrict__ deg) {
    int e = blockIdx.x * blockDim.x + threadIdx.x;
    if (e < E) atomicAdd(&deg[dst[e]], 1);
}

__global__ void dinv_kernel(const int* __restrict__ deg, float* __restrict__ dinv, int n) {
    int i = blockIdx.x * blockDim.x + threadIdx.x;
    if (i < n) dinv[i] = rsqrtf((float)(deg[i] + 1));  // +1 = self-loop
}

// Single-block exclusive scan of deg[0..n) -> rowptr[0..n], rowptr[n] = total.
__global__ __launch_bounds__(1024) void scan_kernel(const int* __restrict__ deg,
                                                    int* __restrict__ rowptr, int n) {
    __shared__ int wsum[16];
    __shared__ int s_carry;
    const int lane = threadIdx.x & 63;
    const int wid  = threadIdx.x >> 6;
    if (threadIdx.x == 0) s_carry = 0;
    __syncthreads();
    for (int base = 0; base < n; base += 1024) {
        int i = base + (int)threadIdx.x;
        int v = (i < n) ? deg[i] : 0;
        // wave-level inclusive scan
        int sc = v;
        #pragma unroll
        for (int off = 1; off < 64; off <<= 1) {
            int t = __shfl_up(sc, off);
            if (lane >= off) sc += t;
        }
        if (lane == 63) wsum[wid] = sc;
        __syncthreads();
        int wprefix = 0;
        for (int k = 0; k < 16; ++k)
            if (k < wid) wprefix += wsum[k];
        int carry = s_carry;
        if (i < n) rowptr[i] = carry + wprefix + (sc - v);
        __syncthreads();                 // all reads of s_carry/wsum done
        if (threadIdx.x == 0) {
            int tot = 0;
            for (int k = 0; k < 16; ++k) tot += wsum[k];
            s_carry = carry + tot;
        }
        __syncthreads();                 // publish s_carry before next chunk
    }
    if (threadIdx.x == 0) rowptr[n] = s_carry;
}

// Scatter edges into dst-sorted CSR; value = dinv[src] packed alongside src.
__global__ void fill_csr_kernel(const int* __restrict__ src, const int* __restrict__ dst, int E,
                                const int* __restrict__ rowptr, int* __restrict__ cursor,
                                const float* __restrict__ dinv, int2* __restrict__ csr) {
    int e = blockIdx.x * blockDim.x + threadIdx.x;
    if (e < E) {
        int d = dst[e], s = src[e];
        int pos = rowptr[d] + atomicAdd(&cursor[d], 1);
        csr[pos] = make_int2(s, __float_as_int(dinv[s]));
    }
}

// Y[n,96] = X[n,96] @ W[96,96].  block = (96,4), one output per thread.
__global__ __launch_bounds__(384) void matmul_kernel(const float* __restrict__ X,
                                                     const float* __restrict__ W,
                                                     float* __restrict__ Y, int n) {
    __shared__ float Wl[D * D];
    __shared__ float Xs[4][D];
    const int tid = threadIdx.y * D + threadIdx.x;
    for (int i = tid; i < D * D; i += 384) Wl[i] = W[i];
    const int row = blockIdx.x * 4 + threadIdx.y;
    if (row < n) Xs[threadIdx.y][threadIdx.x] = X[(size_t)row * D + threadIdx.x];
    __syncthreads();
    if (row < n) {
        float acc = 0.f;
        #pragma unroll
        for (int k = 0; k < D; ++k)
            acc += Xs[threadIdx.y][k] * Wl[k * D + threadIdx.x];
        Y[(size_t)row * D + threadIdx.x] = acc;
    }
}

// out[i,f] = prelu( dinv[i]*sum_e dinv[src_e]*XW[src_e,f] + dinv[i]^2*XW[i,f] + b[f] )
__global__ __launch_bounds__(384) void aggregate_kernel(const float* __restrict__ XW,
                                                        const int2* __restrict__ csr,
                                                        const int* __restrict__ rowptr,
                                                        const float* __restrict__ dinv,
                                                        const float* __restrict__ bias,
                                                        const float* __restrict__ pa,
                                                        float* __restrict__ out, int n) {
    const int i = blockIdx.x * 4 + threadIdx.y;
    const int col = threadIdx.x;
    if (i >= n) return;
    const int beg = rowptr[i], end = rowptr[i + 1];
    float acc = 0.f;
    for (int p = beg; p < end; ++p) {
        int2 e = csr[p];
        acc += __int_as_float(e.y) * XW[(size_t)e.x * D + col];
    }
    const float di = dinv[i];
    float v = di * acc + di * di * XW[(size_t)i * D + col] + bias[col];
    float a = pa[col];
    out[(size_t)i * D + col] = v > 0.f ? v : a * v;
}

extern "C" void kernel_launch(void* const* d_in, const int* in_sizes, int n_in,
                              void* d_out, int out_size, void* d_ws, size_t ws_size,
                              hipStream_t stream) {
    const float* x   = (const float*)d_in[0];
    const int*   ei  = (const int*)d_in[1];
    const float* W1  = (const float*)d_in[2];
    const float* b1  = (const float*)d_in[3];
    const float* W2  = (const float*)d_in[4];
    const float* b2  = (const float*)d_in[5];
    const float* pa  = (const float*)d_in[6];
    const int n = in_sizes[0] / D;
    const int E = in_sizes[1] / 2;
    const int* srcp = ei;
    const int* dstp = ei + E;

    char* w = (char*)d_ws;
    int*   deg    = (int*)w;   w += alignup((size_t)n * 4);
    float* dinv   = (float*)w; w += alignup((size_t)n * 4);
    int*   rowptr = (int*)w;   w += alignup((size_t)(n + 1) * 4);
    int*   cursor = (int*)w;   w += alignup((size_t)n * 4);
    int2*  csr    = (int2*)w;  w += alignup((size_t)E * 8);
    float* xw     = (float*)w; w += alignup((size_t)n * D * 4);
    float* out    = (float*)d_out;

    hipMemsetAsync(deg, 0, (size_t)n * 4, stream);
    hipMemsetAsync(cursor, 0, (size_t)n * 4, stream);

    const int tb = 256;
    count_deg_kernel<<<(E + tb - 1) / tb, tb, 0, stream>>>(dstp, E, deg);
    dinv_kernel<<<(n + tb - 1) / tb, tb, 0, stream>>>(deg, dinv, n);
    scan_kernel<<<1, 1024, 0, stream>>>(deg, rowptr, n);
    fill_csr_kernel<<<(E + tb - 1) / tb, tb, 0, stream>>>(srcp, dstp, E, rowptr, cursor, dinv, csr);

    dim3 blk(D, 4);
    const int nb = (n + 3) / 4;
    matmul_kernel<<<nb, blk, 0, stream>>>(x, W1, xw, n);
    aggregate_kernel<<<nb, blk, 0, stream>>>(xw, csr, rowptr, dinv, b1, pa, out, n);
    matmul_kernel<<<nb, blk, 0, stream>>>(out, W2, xw, n);
    aggregate_kernel<<<nb, blk, 0, stream>>>(xw, csr, rowptr, dinv, b2, pa, out, n);
}

// Round 2
// 274.730 us; speedup vs baseline: 1.9048x; 1.9048x over previous
//
#include <hip/hip_runtime.h>

#define D 96
#define D4 24

static inline size_t alignup(size_t x) { return (x + 255) & ~size_t(255); }

__device__ inline float4 f4fma(float s, float4 a, float4 acc) {
    acc.x = fmaf(s, a.x, acc.x);
    acc.y = fmaf(s, a.y, acc.y);
    acc.z = fmaf(s, a.z, acc.z);
    acc.w = fmaf(s, a.w, acc.w);
    return acc;
}

__global__ void count_deg_kernel(const int* __restrict__ dst, int E, int* __restrict__ deg) {
    int e = blockIdx.x * blockDim.x + threadIdx.x;
    if (e < E) atomicAdd(&deg[dst[e]], 1);
}

__global__ void dinv_kernel(const int* __restrict__ deg, float* __restrict__ dinv, int n) {
    int i = blockIdx.x * blockDim.x + threadIdx.x;
    if (i < n) dinv[i] = rsqrtf((float)(deg[i] + 1));  // +1 = self-loop
}

// Single-block exclusive scan of deg[0..n) -> rowptr[0..n], rowptr[n] = total.
__global__ __launch_bounds__(1024) void scan_kernel(const int* __restrict__ deg,
                                                    int* __restrict__ rowptr, int n) {
    __shared__ int wsum[16];
    __shared__ int s_carry;
    const int lane = threadIdx.x & 63;
    const int wid  = threadIdx.x >> 6;
    if (threadIdx.x == 0) s_carry = 0;
    __syncthreads();
    for (int base = 0; base < n; base += 1024) {
        int i = base + (int)threadIdx.x;
        int v = (i < n) ? deg[i] : 0;
        int sc = v;
        #pragma unroll
        for (int off = 1; off < 64; off <<= 1) {
            int t = __shfl_up(sc, off);
            if (lane >= off) sc += t;
        }
        if (lane == 63) wsum[wid] = sc;
        __syncthreads();
        int wprefix = 0;
        for (int k = 0; k < 16; ++k)
            if (k < wid) wprefix += wsum[k];
        int carry = s_carry;
        if (i < n) rowptr[i] = carry + wprefix + (sc - v);
        __syncthreads();
        if (threadIdx.x == 0) {
            int tot = 0;
            for (int k = 0; k < 16; ++k) tot += wsum[k];
            s_carry = carry + tot;
        }
        __syncthreads();
    }
    if (threadIdx.x == 0) rowptr[n] = s_carry;
}

__global__ void fill_csr_kernel(const int* __restrict__ src, const int* __restrict__ dst, int E,
                                const int* __restrict__ rowptr, int* __restrict__ cursor,
                                const float* __restrict__ dinv, int2* __restrict__ csr) {
    int e = blockIdx.x * blockDim.x + threadIdx.x;
    if (e < E) {
        int d = dst[e], s = src[e];
        int pos = rowptr[d] + atomicAdd(&cursor[d], 1);
        csr[pos] = make_int2(s, __float_as_int(dinv[s]));
    }
}

// Y[n,96] = X[n,96] @ W[96,96].
// block (24,8)=192 threads, 64 rows/block; thread computes 8 rows x 4 cols.
// X staged transposed in LDS (XOR-swizzled, conflict-free b128 reads);
// W streamed from global (L1/L2-resident, shared across all blocks).
__global__ __launch_bounds__(192) void matmul_kernel(const float* __restrict__ X,
                                                     const float* __restrict__ W,
                                                     float* __restrict__ Y, int n) {
    __shared__ float XsT[96 * 64];
    const int t = threadIdx.x;        // 0..23 col-group (float4)
    const int y = threadIdx.y;        // 0..7 row-group
    const int tid = y * 24 + t;
    const int row0 = blockIdx.x * 64;
    const float4* X4 = (const float4*)X;

    // stage X^T: element (row r, col c) stored at XsT[c*64 + (r ^ ((c>>2 & 15)<<2))]
    for (int i = tid; i < 64 * 24; i += 192) {
        int r = i / 24, c4 = i % 24;
        float4 v = make_float4(0.f, 0.f, 0.f, 0.f);
        if (row0 + r < n) v = X4[(size_t)(row0 + r) * D4 + c4];
        int rs = r ^ ((c4 & 15) << 2);
        XsT[(c4 * 4 + 0) * 64 + rs] = v.x;
        XsT[(c4 * 4 + 1) * 64 + rs] = v.y;
        XsT[(c4 * 4 + 2) * 64 + rs] = v.z;
        XsT[(c4 * 4 + 3) * 64 + rs] = v.w;
    }
    __syncthreads();

    const float4* W4 = (const float4*)W;
    float4 acc[8];
    #pragma unroll
    for (int r = 0; r < 8; ++r) acc[r] = make_float4(0.f, 0.f, 0.f, 0.f);
    const int rbase = y * 8;

    #pragma unroll 8
    for (int k = 0; k < 96; ++k) {
        float4 w = W4[k * D4 + t];
        int base0 = (rbase ^ (((k >> 2) & 15) << 2));
        float4 xa = *(const float4*)&XsT[k * 64 + base0];
        float4 xb = *(const float4*)&XsT[k * 64 + (base0 ^ 4)];
        acc[0] = f4fma(xa.x, w, acc[0]);
        acc[1] = f4fma(xa.y, w, acc[1]);
        acc[2] = f4fma(xa.z, w, acc[2]);
        acc[3] = f4fma(xa.w, w, acc[3]);
        acc[4] = f4fma(xb.x, w, acc[4]);
        acc[5] = f4fma(xb.y, w, acc[5]);
        acc[6] = f4fma(xb.z, w, acc[6]);
        acc[7] = f4fma(xb.w, w, acc[7]);
    }

    #pragma unroll
    for (int r = 0; r < 8; ++r) {
        int row = row0 + rbase + r;
        if (row < n) ((float4*)Y)[(size_t)row * D4 + t] = acc[r];
    }
}

// out[i,:] = prelu( dinv[i]*sum_e dinv[src]*XW[src,:] + dinv[i]^2*XW[i,:] + b )
// block (24,16): 24 threads/node (float4 cols), 16 nodes/block, edge loop unrolled x4.
__global__ __launch_bounds__(384) void aggregate_kernel(const float4* __restrict__ XW4,
                                                        const int2* __restrict__ csr,
                                                        const int* __restrict__ rowptr,
                                                        const float* __restrict__ dinv,
                                                        const float4* __restrict__ b4,
                                                        const float4* __restrict__ pa4,
                                                        float4* __restrict__ out4, int n) {
    const int i = blockIdx.x * 16 + threadIdx.y;
    const int t = threadIdx.x;  // 0..23
    if (i >= n) return;
    const int beg = rowptr[i], end = rowptr[i + 1];
    float4 acc = make_float4(0.f, 0.f, 0.f, 0.f);
    int p = beg;
    for (; p + 4 <= end; p += 4) {
        int2 e0 = csr[p + 0];
        int2 e1 = csr[p + 1];
        int2 e2 = csr[p + 2];
        int2 e3 = csr[p + 3];
        float4 r0 = XW4[(size_t)e0.x * D4 + t];
        float4 r1 = XW4[(size_t)e1.x * D4 + t];
        float4 r2 = XW4[(size_t)e2.x * D4 + t];
        float4 r3 = XW4[(size_t)e3.x * D4 + t];
        acc = f4fma(__int_as_float(e0.y), r0, acc);
        acc = f4fma(__int_as_float(e1.y), r1, acc);
        acc = f4fma(__int_as_float(e2.y), r2, acc);
        acc = f4fma(__int_as_float(e3.y), r3, acc);
    }
    for (; p < end; ++p) {
        int2 e = csr[p];
        acc = f4fma(__int_as_float(e.y), XW4[(size_t)e.x * D4 + t], acc);
    }
    const float di = dinv[i];
    float4 self = XW4[(size_t)i * D4 + t];
    float4 b = b4[t], a = pa4[t];
    float4 v;
    v.x = fmaf(di, acc.x, di * di * self.x) + b.x;
    v.y = fmaf(di, acc.y, di * di * self.y) + b.y;
    v.z = fmaf(di, acc.z, di * di * self.z) + b.z;
    v.w = fmaf(di, acc.w, di * di * self.w) + b.w;
    v.x = v.x > 0.f ? v.x : a.x * v.x;
    v.y = v.y > 0.f ? v.y : a.y * v.y;
    v.z = v.z > 0.f ? v.z : a.z * v.z;
    v.w = v.w > 0.f ? v.w : a.w * v.w;
    out4[(size_t)i * D4 + t] = v;
}

extern "C" void kernel_launch(void* const* d_in, const int* in_sizes, int n_in,
                              void* d_out, int out_size, void* d_ws, size_t ws_size,
                              hipStream_t stream) {
    const float* x   = (const float*)d_in[0];
    const int*   ei  = (const int*)d_in[1];
    const float* W1  = (const float*)d_in[2];
    const float* b1  = (const float*)d_in[3];
    const float* W2  = (const float*)d_in[4];
    const float* b2  = (const float*)d_in[5];
    const float* pa  = (const float*)d_in[6];
    const int n = in_sizes[0] / D;
    const int E = in_sizes[1] / 2;
    const int* srcp = ei;
    const int* dstp = ei + E;

    char* w = (char*)d_ws;
    int*   deg    = (int*)w;   w += alignup((size_t)n * 4);
    float* dinv   = (float*)w; w += alignup((size_t)n * 4);
    int*   rowptr = (int*)w;   w += alignup((size_t)(n + 1) * 4);
    int*   cursor = (int*)w;   w += alignup((size_t)n * 4);
    int2*  csr    = (int2*)w;  w += alignup((size_t)E * 8);
    float* xw     = (float*)w; w += alignup((size_t)n * D * 4);
    float* out    = (float*)d_out;

    hipMemsetAsync(deg, 0, (size_t)n * 4, stream);
    hipMemsetAsync(cursor, 0, (size_t)n * 4, stream);

    const int tb = 256;
    count_deg_kernel<<<(E + tb - 1) / tb, tb, 0, stream>>>(dstp, E, deg);
    dinv_kernel<<<(n + tb - 1) / tb, tb, 0, stream>>>(deg, dinv, n);
    scan_kernel<<<1, 1024, 0, stream>>>(deg, rowptr, n);
    fill_csr_kernel<<<(E + tb - 1) / tb, tb, 0, stream>>>(srcp, dstp, E, rowptr, cursor, dinv, csr);

    dim3 mblk(24, 8);
    const int mgrid = (n + 63) / 64;
    dim3 ablk(24, 16);
    const int agrid = (n + 15) / 16;

    matmul_kernel<<<mgrid, mblk, 0, stream>>>(x, W1, xw, n);
    aggregate_kernel<<<agrid, ablk, 0, stream>>>((const float4*)xw, csr, rowptr, dinv,
                                                 (const float4*)b1, (const float4*)pa, (float4*)out, n);
    matmul_kernel<<<mgrid, mblk, 0, stream>>>(out, W2, xw, n);
    aggregate_kernel<<<agrid, ablk, 0, stream>>>((const float4*)xw, csr, rowptr, dinv,
                                                 (const float4*)b2, (const float4*)pa, (float4*)out, n);
}

// Round 3
// 229.810 us; speedup vs baseline: 2.2771x; 1.1955x over previous
//
#include <hip/hip_runtime.h>

#define D 96
#define D4 24

static inline size_t alignup(size_t x) { return (x + 255) & ~size_t(255); }

__device__ inline float4 f4fma(float s, float4 a, float4 acc) {
    acc.x = fmaf(s, a.x, acc.x);
    acc.y = fmaf(s, a.y, acc.y);
    acc.z = fmaf(s, a.z, acc.z);
    acc.w = fmaf(s, a.w, acc.w);
    return acc;
}

__global__ void count_deg_kernel(const int* __restrict__ dst, int E, int* __restrict__ deg) {
    int e = blockIdx.x * blockDim.x + threadIdx.x;
    if (e < E) atomicAdd(&deg[dst[e]], 1);
}

// Phase 1: per-block exclusive scan of deg -> rowptr (local), block totals -> bsum.
// Also fused: dinv[i] = rsqrt(deg[i]+1).
__global__ __launch_bounds__(1024) void scan_blocks_kernel(const int* __restrict__ deg,
                                                           int* __restrict__ rowptr,
                                                           float* __restrict__ dinv,
                                                           int* __restrict__ bsum, int n) {
    __shared__ int wsum[16];
    const int i = blockIdx.x * 1024 + threadIdx.x;
    const int lane = threadIdx.x & 63;
    const int wid  = threadIdx.x >> 6;
    int v = (i < n) ? deg[i] : 0;
    if (i < n) dinv[i] = rsqrtf((float)(v + 1));  // +1 = self-loop
    int sc = v;
    #pragma unroll
    for (int off = 1; off < 64; off <<= 1) {
        int t = __shfl_up(sc, off);
        if (lane >= off) sc += t;
    }
    if (lane == 63) wsum[wid] = sc;
    __syncthreads();
    int wprefix = 0;
    #pragma unroll
    for (int k = 0; k < 16; ++k)
        if (k < wid) wprefix += wsum[k];
    if (i < n) rowptr[i] = wprefix + (sc - v);
    if (threadIdx.x == 1023) bsum[blockIdx.x] = wprefix + sc;
}

// Phase 2: one block scans the block sums (nb <= 1024); writes exclusive offsets
// to boff and the grand total to rowptr[n].
__global__ __launch_bounds__(1024) void scan_partials_kernel(const int* __restrict__ bsum,
                                                             int* __restrict__ boff,
                                                             int* __restrict__ rowptr,
                                                             int nb, int n) {
    __shared__ int wsum[16];
    const int lane = threadIdx.x & 63;
    const int wid  = threadIdx.x >> 6;
    int v = ((int)threadIdx.x < nb) ? bsum[threadIdx.x] : 0;
    int sc = v;
    #pragma unroll
    for (int off = 1; off < 64; off <<= 1) {
        int t = __shfl_up(sc, off);
        if (lane >= off) sc += t;
    }
    if (lane == 63) wsum[wid] = sc;
    __syncthreads();
    int wprefix = 0;
    #pragma unroll
    for (int k = 0; k < 16; ++k)
        if (k < wid) wprefix += wsum[k];
    if ((int)threadIdx.x < nb) boff[threadIdx.x] = wprefix + (sc - v);
    if ((int)threadIdx.x == nb - 1) rowptr[n] = wprefix + sc;
}

// Phase 3: add block offsets.
__global__ __launch_bounds__(1024) void scan_add_kernel(int* __restrict__ rowptr,
                                                        const int* __restrict__ boff, int n) {
    int i = blockIdx.x * 1024 + threadIdx.x;
    if (i < n) rowptr[i] += boff[blockIdx.x];
}

__global__ void fill_csr_kernel(const int* __restrict__ src, const int* __restrict__ dst, int E,
                                const int* __restrict__ rowptr, int* __restrict__ cursor,
                                const float* __restrict__ dinv, int2* __restrict__ csr) {
    int e = blockIdx.x * blockDim.x + threadIdx.x;
    if (e < E) {
        int d = dst[e], s = src[e];
        int pos = rowptr[d] + atomicAdd(&cursor[d], 1);
        csr[pos] = make_int2(s, __float_as_int(dinv[s]));
    }
}

// Y[n,96] = X[n,96] @ W[96,96].
// block (24,8)=192 threads, 64 rows/block; thread computes 8 rows x 4 cols.
__global__ __launch_bounds__(192) void matmul_kernel(const float* __restrict__ X,
                                                     const float* __restrict__ W,
                                                     float* __restrict__ Y, int n) {
    __shared__ float XsT[96 * 64];
    const int t = threadIdx.x;        // 0..23 col-group (float4)
    const int y = threadIdx.y;        // 0..7 row-group
    const int tid = y * 24 + t;
    const int row0 = blockIdx.x * 64;
    const float4* X4 = (const float4*)X;

    for (int i = tid; i < 64 * 24; i += 192) {
        int r = i / 24, c4 = i % 24;
        float4 v = make_float4(0.f, 0.f, 0.f, 0.f);
        if (row0 + r < n) v = X4[(size_t)(row0 + r) * D4 + c4];
        int rs = r ^ ((c4 & 15) << 2);
        XsT[(c4 * 4 + 0) * 64 + rs] = v.x;
        XsT[(c4 * 4 + 1) * 64 + rs] = v.y;
        XsT[(c4 * 4 + 2) * 64 + rs] = v.z;
        XsT[(c4 * 4 + 3) * 64 + rs] = v.w;
    }
    __syncthreads();

    const float4* W4 = (const float4*)W;
    float4 acc[8];
    #pragma unroll
    for (int r = 0; r < 8; ++r) acc[r] = make_float4(0.f, 0.f, 0.f, 0.f);
    const int rbase = y * 8;

    #pragma unroll 8
    for (int k = 0; k < 96; ++k) {
        float4 w = W4[k * D4 + t];
        int base0 = (rbase ^ (((k >> 2) & 15) << 2));
        float4 xa = *(const float4*)&XsT[k * 64 + base0];
        float4 xb = *(const float4*)&XsT[k * 64 + (base0 ^ 4)];
        acc[0] = f4fma(xa.x, w, acc[0]);
        acc[1] = f4fma(xa.y, w, acc[1]);
        acc[2] = f4fma(xa.z, w, acc[2]);
        acc[3] = f4fma(xa.w, w, acc[3]);
        acc[4] = f4fma(xb.x, w, acc[4]);
        acc[5] = f4fma(xb.y, w, acc[5]);
        acc[6] = f4fma(xb.z, w, acc[6]);
        acc[7] = f4fma(xb.w, w, acc[7]);
    }

    #pragma unroll
    for (int r = 0; r < 8; ++r) {
        int row = row0 + rbase + r;
        if (row < n) ((float4*)Y)[(size_t)row * D4 + t] = acc[r];
    }
}

// out[i,:] = prelu( dinv[i]*sum_e dinv[src]*XW[src,:] + dinv[i]^2*XW[i,:] + b )
__global__ __launch_bounds__(384) void aggregate_kernel(const float4* __restrict__ XW4,
                                                        const int2* __restrict__ csr,
                                                        const int* __restrict__ rowptr,
                                                        const float* __restrict__ dinv,
                                                        const float4* __restrict__ b4,
                                                        const float4* __restrict__ pa4,
                                                        float4* __restrict__ out4, int n) {
    const int i = blockIdx.x * 16 + threadIdx.y;
    const int t = threadIdx.x;  // 0..23
    if (i >= n) return;
    const int beg = rowptr[i], end = rowptr[i + 1];
    float4 acc = make_float4(0.f, 0.f, 0.f, 0.f);
    int p = beg;
    for (; p + 4 <= end; p += 4) {
        int2 e0 = csr[p + 0];
        int2 e1 = csr[p + 1];
        int2 e2 = csr[p + 2];
        int2 e3 = csr[p + 3];
        float4 r0 = XW4[(size_t)e0.x * D4 + t];
        float4 r1 = XW4[(size_t)e1.x * D4 + t];
        float4 r2 = XW4[(size_t)e2.x * D4 + t];
        float4 r3 = XW4[(size_t)e3.x * D4 + t];
        acc = f4fma(__int_as_float(e0.y), r0, acc);
        acc = f4fma(__int_as_float(e1.y), r1, acc);
        acc = f4fma(__int_as_float(e2.y), r2, acc);
        acc = f4fma(__int_as_float(e3.y), r3, acc);
    }
    for (; p < end; ++p) {
        int2 e = csr[p];
        acc = f4fma(__int_as_float(e.y), XW4[(size_t)e.x * D4 + t], acc);
    }
    const float di = dinv[i];
    float4 self = XW4[(size_t)i * D4 + t];
    float4 b = b4[t], a = pa4[t];
    float4 v;
    v.x = fmaf(di, acc.x, di * di * self.x) + b.x;
    v.y = fmaf(di, acc.y, di * di * self.y) + b.y;
    v.z = fmaf(di, acc.z, di * di * self.z) + b.z;
    v.w = fmaf(di, acc.w, di * di * self.w) + b.w;
    v.x = v.x > 0.f ? v.x : a.x * v.x;
    v.y = v.y > 0.f ? v.y : a.y * v.y;
    v.z = v.z > 0.f ? v.z : a.z * v.z;
    v.w = v.w > 0.f ? v.w : a.w * v.w;
    out4[(size_t)i * D4 + t] = v;
}

extern "C" void kernel_launch(void* const* d_in, const int* in_sizes, int n_in,
                              void* d_out, int out_size, void* d_ws, size_t ws_size,
                              hipStream_t stream) {
    const float* x   = (const float*)d_in[0];
    const int*   ei  = (const int*)d_in[1];
    const float* W1  = (const float*)d_in[2];
    const float* b1  = (const float*)d_in[3];
    const float* W2  = (const float*)d_in[4];
    const float* b2  = (const float*)d_in[5];
    const float* pa  = (const float*)d_in[6];
    const int n = in_sizes[0] / D;
    const int E = in_sizes[1] / 2;
    const int* srcp = ei;
    const int* dstp = ei + E;

    char* w = (char*)d_ws;
    int*   deg    = (int*)w;   w += alignup((size_t)n * 4);
    float* dinv   = (float*)w; w += alignup((size_t)n * 4);
    int*   rowptr = (int*)w;   w += alignup((size_t)(n + 1) * 4);
    int*   cursor = (int*)w;   w += alignup((size_t)n * 4);
    int*   bsum   = (int*)w;   w += alignup(1024 * 4);
    int*   boff   = (int*)w;   w += alignup(1024 * 4);
    int2*  csr    = (int2*)w;  w += alignup((size_t)E * 8);
    float* xw     = (float*)w; w += alignup((size_t)n * D * 4);
    float* out    = (float*)d_out;

    hipMemsetAsync(deg, 0, (size_t)n * 4, stream);
    hipMemsetAsync(cursor, 0, (size_t)n * 4, stream);

    const int tb = 256;
    const int nb = (n + 1023) / 1024;
    count_deg_kernel<<<(E + tb - 1) / tb, tb, 0, stream>>>(dstp, E, deg);
    scan_blocks_kernel<<<nb, 1024, 0, stream>>>(deg, rowptr, dinv, bsum, n);
    scan_partials_kernel<<<1, 1024, 0, stream>>>(bsum, boff, rowptr, nb, n);
    scan_add_kernel<<<nb, 1024, 0, stream>>>(rowptr, boff, n);
    fill_csr_kernel<<<(E + tb - 1) / tb, tb, 0, stream>>>(srcp, dstp, E, rowptr, cursor, dinv, csr);

    dim3 mblk(24, 8);
    const int mgrid = (n + 63) / 64;
    dim3 ablk(24, 16);
    const int agrid = (n + 15) / 16;

    matmul_kernel<<<mgrid, mblk, 0, stream>>>(x, W1, xw, n);
    aggregate_kernel<<<agrid, ablk, 0, stream>>>((const float4*)xw, csr, rowptr, dinv,
                                                 (const float4*)b1, (const float4*)pa, (float4*)out, n);
    matmul_kernel<<<mgrid, mblk, 0, stream>>>(out, W2, xw, n);
    aggregate_kernel<<<agrid, ablk, 0, stream>>>((const float4*)xw, csr, rowptr, dinv,
                                                 (const float4*)b2, (const float4*)pa, (float4*)out, n);
}